// Round 22
// baseline (161.323 us; speedup 1.0000x reference)
//
#include <hip/hip_runtime.h>
#include <hip/hip_bf16.h>

#define B 2
#define S 2048
#define E 128
#define H 8
#define HD 16
#define BH (B*H)

#define RPB 16   // rows per block (qkv_proj)
#define QT 64    // queries per block (attn)
#define NQ 4     // queries per lane
#define KT 128   // key tile
#define KPAD 20  // padded row stride (floats) for K/V LDS tiles

// ---- Pass 0: QKV projection, 16 rows/block. Faithful d8h split. ----
__global__ __launch_bounds__(128) void qkv_proj(
    const float* __restrict__ x,
    const float* __restrict__ wq,
    const float* __restrict__ wk,
    const float* __restrict__ wv,
    float* __restrict__ Q, float* __restrict__ K, float* __restrict__ V)
{
    __shared__ float xs[RPB][E];
    const int row0 = blockIdx.x * RPB;
    const int c    = threadIdx.x;        // 0..127 output column
    #pragma unroll
    for (int rr = 0; rr < RPB; ++rr)
        xs[rr][c] = x[(size_t)(row0 + rr) * E + c];
    __syncthreads();

    float aq[RPB], ak[RPB], av[RPB];
    #pragma unroll
    for (int rr = 0; rr < RPB; ++rr) { aq[rr] = 0.f; ak[rr] = 0.f; av[rr] = 0.f; }

    for (int i = 0; i < E; ++i) {
        const float wqv = wq[i * E + c];
        const float wkv = wk[i * E + c];
        const float wvv = wv[i * E + c];
        #pragma unroll
        for (int rr = 0; rr < RPB; ++rr) {
            const float xv = xs[rr][i];
            aq[rr] = fmaf(xv, wqv, aq[rr]);
            ak[rr] = fmaf(xv, wkv, ak[rr]);
            av[rr] = fmaf(xv, wvv, av[rr]);
        }
    }

    const int h = c & 7, d = c >> 3;     // faithful split: col c = d*8+h
    #pragma unroll
    for (int rr = 0; rr < RPB; ++rr) {
        const int row = row0 + rr;
        const int b = row >> 11, s = row & 2047;
        const size_t off = (((size_t)(b * H + h)) * S + s) * HD + d;
        Q[off] = aq[rr] * 0.25f;
        K[off] = ak[rr];
        V[off] = av[rr];
    }
}

// ---- Pass 1: flash attention, f32, NQ=4 register-blocked queries. ----
// 256 threads = 16 query-quads x 16 key-lanes. Each lane: 4 queries,
// 8 keys/tile. K/V LDS rows read once per key, shared across 4 queries
// (LDS bytes/pair 128 -> 32). Tile-deferred softmax per query.
__global__ __launch_bounds__(256) void attn(
    const float* __restrict__ Q, const float* __restrict__ K,
    const float* __restrict__ V,
    const int* __restrict__ src_mask, const int* __restrict__ masked_p,
    float* __restrict__ out)
{
    __shared__ float Ks[KT * KPAD];
    __shared__ float Vs[KT * KPAD];
    __shared__ float Ms[KT];

    const int bh    = blockIdx.y;
    const int b     = bh >> 3;
    const int h     = bh & 7;
    const int qtile = blockIdx.x;        // 0..31
    const int tid   = threadIdx.x;
    const int qg    = tid >> 4;          // 0..15 query quad
    const int kl    = tid & 15;          // key lane
    const int masked = *masked_p;
    const int qrow0 = qtile * QT + qg * NQ;

    // 4 query rows from global (16 lanes share rows -> L1 broadcast)
    float4 q[NQ][4];
    #pragma unroll
    for (int qq = 0; qq < NQ; ++qq) {
        const float4* qg4 = (const float4*)(Q + ((size_t)bh * S + qrow0 + qq) * HD);
        q[qq][0] = qg4[0]; q[qq][1] = qg4[1]; q[qq][2] = qg4[2]; q[qq][3] = qg4[3];
    }

    float m[NQ], l[NQ];
    float acc[NQ][HD];
    #pragma unroll
    for (int qq = 0; qq < NQ; ++qq) {
        m[qq] = -INFINITY; l[qq] = 0.f;
        #pragma unroll
        for (int d = 0; d < HD; ++d) acc[qq][d] = 0.f;
    }

    for (int kt = 0; kt < S / KT; ++kt) {
        __syncthreads();   // previous tile fully consumed
        {
            const float4* k4 = (const float4*)(K + ((size_t)bh * S + kt * KT) * HD);
            const float4* v4 = (const float4*)(V + ((size_t)bh * S + kt * KT) * HD);
            #pragma unroll
            for (int r = 0; r < 2; ++r) {
                const int idx4 = tid + r * 256;          // 0..511
                const int row = idx4 >> 2, c4 = idx4 & 3;
                ((float4*)(Ks + row * KPAD))[c4] = k4[idx4];
                ((float4*)(Vs + row * KPAD))[c4] = v4[idx4];
            }
            if (tid < KT) {
                float am = 0.f;
                if (!masked && src_mask[b * S + kt * KT + tid] == 0) am = -1000.f;
                Ms[tid] = am;
            }
        }
        __syncthreads();

        // phase 1: scores s[qq][jj], K row read once per key
        float s[NQ][8];
        #pragma unroll
        for (int jj = 0; jj < 8; ++jj) {
            const int j = kl + jj * 16;
            const float4* k4 = (const float4*)(Ks + j * KPAD);
            const float4 ka = k4[0], kb = k4[1], kc = k4[2], kd = k4[3];
            const float ms = Ms[j];
            #pragma unroll
            for (int qq = 0; qq < NQ; ++qq) {
                float dot;
                dot = q[qq][0].x * ka.x;
                dot = fmaf(q[qq][0].y, ka.y, dot);
                dot = fmaf(q[qq][0].z, ka.z, dot);
                dot = fmaf(q[qq][0].w, ka.w, dot);
                dot = fmaf(q[qq][1].x, kb.x, dot);
                dot = fmaf(q[qq][1].y, kb.y, dot);
                dot = fmaf(q[qq][1].z, kb.z, dot);
                dot = fmaf(q[qq][1].w, kb.w, dot);
                dot = fmaf(q[qq][2].x, kc.x, dot);
                dot = fmaf(q[qq][2].y, kc.y, dot);
                dot = fmaf(q[qq][2].z, kc.z, dot);
                dot = fmaf(q[qq][2].w, kc.w, dot);
                dot = fmaf(q[qq][3].x, kd.x, dot);
                dot = fmaf(q[qq][3].y, kd.y, dot);
                dot = fmaf(q[qq][3].z, kd.z, dot);
                dot = fmaf(q[qq][3].w, kd.w, dot);
                s[qq][jj] = dot + ms;
            }
        }

        // phase 2: per-query tile max, at-most-one rescale
        #pragma unroll
        for (int qq = 0; qq < NQ; ++qq) {
            float tm = s[qq][0];
            #pragma unroll
            for (int jj = 1; jj < 8; ++jj) tm = fmaxf(tm, s[qq][jj]);
            if (tm > m[qq]) {
                const float alpha = __expf(m[qq] - tm);  // exp(-inf)=0 at kt=0
                l[qq] *= alpha;
                #pragma unroll
                for (int d = 0; d < HD; ++d) acc[qq][d] *= alpha;
                m[qq] = tm;
            }
        }

        // phase 3: V row read once per key, shared across 4 queries
        #pragma unroll
        for (int jj = 0; jj < 8; ++jj) {
            const int j = kl + jj * 16;
            const float4* v4 = (const float4*)(Vs + j * KPAD);
            const float4 va = v4[0], vb = v4[1], vc = v4[2], vd = v4[3];
            #pragma unroll
            for (int qq = 0; qq < NQ; ++qq) {
                const float p = __expf(s[qq][jj] - m[qq]);
                l[qq] += p;
                acc[qq][0]  = fmaf(p, va.x, acc[qq][0]);
                acc[qq][1]  = fmaf(p, va.y, acc[qq][1]);
                acc[qq][2]  = fmaf(p, va.z, acc[qq][2]);
                acc[qq][3]  = fmaf(p, va.w, acc[qq][3]);
                acc[qq][4]  = fmaf(p, vb.x, acc[qq][4]);
                acc[qq][5]  = fmaf(p, vb.y, acc[qq][5]);
                acc[qq][6]  = fmaf(p, vb.z, acc[qq][6]);
                acc[qq][7]  = fmaf(p, vb.w, acc[qq][7]);
                acc[qq][8]  = fmaf(p, vc.x, acc[qq][8]);
                acc[qq][9]  = fmaf(p, vc.y, acc[qq][9]);
                acc[qq][10] = fmaf(p, vc.z, acc[qq][10]);
                acc[qq][11] = fmaf(p, vc.w, acc[qq][11]);
                acc[qq][12] = fmaf(p, vd.x, acc[qq][12]);
                acc[qq][13] = fmaf(p, vd.y, acc[qq][13]);
                acc[qq][14] = fmaf(p, vd.z, acc[qq][14]);
                acc[qq][15] = fmaf(p, vd.w, acc[qq][15]);
            }
        }
    }

    // merge the 16 key-lanes (consecutive lanes, same wave)
    #pragma unroll
    for (int off = 1; off < 16; off <<= 1) {
        #pragma unroll
        for (int qq = 0; qq < NQ; ++qq) {
            const float m2 = __shfl_xor(m[qq], off);
            const float l2 = __shfl_xor(l[qq], off);
            const float mn = fmaxf(m[qq], m2);
            const float a1 = __expf(m[qq] - mn);
            const float a2 = __expf(m2 - mn);
            l[qq] = l[qq] * a1 + l2 * a2;
            #pragma unroll
            for (int d = 0; d < HD; ++d) {
                const float x2 = __shfl_xor(acc[qq][d], off);
                acc[qq][d] = acc[qq][d] * a1 + x2 * a2;
            }
            m[qq] = mn;
        }
    }

    if (kl == 0) {
        #pragma unroll
        for (int qq = 0; qq < NQ; ++qq) {
            const int s = qrow0 + qq;
            const float inv = 1.f / l[qq];
            // faithful merge: out[b][s][d*8+h], f32
            float* o = out + ((size_t)(b * S + s)) * E + h;
            #pragma unroll
            for (int d = 0; d < HD; ++d)
                o[d * H] = acc[qq][d] * inv;
        }
    }
}

extern "C" void kernel_launch(void* const* d_in, const int* in_sizes, int n_in,
                              void* d_out, int out_size, void* d_ws, size_t ws_size,
                              hipStream_t stream) {
    // size-signature resolution; same-size buffers keep dict relative order
    int ix = 0, im0 = -1, isc = -1, iw[3] = {-1, -1, -1}, nw = 0;
    for (int i = 0; i < n_in; ++i) {
        const int sz = in_sizes[i];
        if (sz == B * S * E) ix = i;
        else if (sz == B * S) { if (im0 < 0) im0 = i; }
        else if (sz == E * E) { if (nw < 3) iw[nw++] = i; }
        else if (sz == 1 && isc < 0) isc = i;
    }
    if (im0 < 0) im0 = 1;
    if (isc < 0) isc = 3;
    if (nw < 3) { iw[0] = n_in - 3; iw[1] = n_in - 2; iw[2] = n_in - 1; }

    const float* x        = (const float*)d_in[ix];
    const int*   src_mask = (const int*)d_in[im0];
    const int*   masked_p = (const int*)d_in[isc];
    const float* wq       = (const float*)d_in[iw[0]];
    const float* wk       = (const float*)d_in[iw[1]];
    const float* wv       = (const float*)d_in[iw[2]];
    float*       out      = (float*)d_out;

    float* Qw = (float*)d_ws;                    // [BH][S][HD] each, 2 MB
    float* Kw = Qw + (size_t)BH * S * HD;
    float* Vw = Kw + (size_t)BH * S * HD;

    qkv_proj<<<B * S / RPB, 128, 0, stream>>>(x, wq, wk, wv, Qw, Kw, Vw);
    attn<<<dim3(S / QT, BH), 256, 0, stream>>>(Qw, Kw, Vw, src_mask, masked_p, out);
}

// Round 23
// 130.794 us; speedup vs baseline: 1.2334x; 1.2334x over previous
//
#include <hip/hip_runtime.h>
#include <hip/hip_bf16.h>

#define B 2
#define S 2048
#define E 128
#define H 8
#define HD 16
#define BH (B*H)

#define RPB 8    // rows per block (qkv_proj)
#define QT 32    // queries per block (attn)
#define NQ 4     // queries per lane
#define NK 4     // keys per lane per tile (KT / 32 key-lanes)
#define KT 128   // key tile
#define KPAD 20  // padded row stride (floats) for K/V LDS tiles

// ---- Pass 0: QKV projection, 8 rows/block. Faithful d8h split. ----
__global__ __launch_bounds__(128) void qkv_proj(
    const float* __restrict__ x,
    const float* __restrict__ wq,
    const float* __restrict__ wk,
    const float* __restrict__ wv,
    float* __restrict__ Q, float* __restrict__ K, float* __restrict__ V)
{
    __shared__ float xs[RPB][E];
    const int row0 = blockIdx.x * RPB;
    const int c    = threadIdx.x;        // 0..127 output column
    #pragma unroll
    for (int rr = 0; rr < RPB; ++rr)
        xs[rr][c] = x[(size_t)(row0 + rr) * E + c];
    __syncthreads();

    float aq[RPB], ak[RPB], av[RPB];
    #pragma unroll
    for (int rr = 0; rr < RPB; ++rr) { aq[rr] = 0.f; ak[rr] = 0.f; av[rr] = 0.f; }

    for (int i = 0; i < E; ++i) {
        const float wqv = wq[i * E + c];
        const float wkv = wk[i * E + c];
        const float wvv = wv[i * E + c];
        #pragma unroll
        for (int rr = 0; rr < RPB; ++rr) {
            const float xv = xs[rr][i];
            aq[rr] = fmaf(xv, wqv, aq[rr]);
            ak[rr] = fmaf(xv, wkv, ak[rr]);
            av[rr] = fmaf(xv, wvv, av[rr]);
        }
    }

    const int h = c & 7, d = c >> 3;     // faithful split: col c = d*8+h
    #pragma unroll
    for (int rr = 0; rr < RPB; ++rr) {
        const int row = row0 + rr;
        const int b = row >> 11, s = row & 2047;
        const size_t off = (((size_t)(b * H + h)) * S + s) * HD + d;
        Q[off] = aq[rr] * 0.25f;
        K[off] = ak[rr];
        V[off] = av[rr];
    }
}

// ---- Pass 1: flash attention, f32, NQ=4 x 32 key-lanes. ----
// 256 threads = 8 query-quads x 32 key-lanes; each lane 4 queries x 4 keys
// per 128-key tile. K/V LDS rows read once per key, shared by 4 queries.
// Tile-deferred softmax (<=1 rescale/tile/query). Grid 1024 blocks.
__global__ __launch_bounds__(256) void attn(
    const float* __restrict__ Q, const float* __restrict__ K,
    const float* __restrict__ V,
    const int* __restrict__ src_mask, const int* __restrict__ masked_p,
    float* __restrict__ out)
{
    __shared__ float Ks[KT * KPAD];
    __shared__ float Vs[KT * KPAD];
    __shared__ float Ms[KT];

    const int bh    = blockIdx.y;
    const int b     = bh >> 3;
    const int h     = bh & 7;
    const int qtile = blockIdx.x;        // 0..63
    const int tid   = threadIdx.x;
    const int qg    = tid >> 5;          // 0..7 query quad
    const int kl    = tid & 31;          // key lane
    const int masked = *masked_p;
    const int qrow0 = qtile * QT + qg * NQ;

    // 4 query rows from global (32 lanes share rows -> L1 broadcast)
    float4 q[NQ][4];
    #pragma unroll
    for (int qq = 0; qq < NQ; ++qq) {
        const float4* qg4 = (const float4*)(Q + ((size_t)bh * S + qrow0 + qq) * HD);
        q[qq][0] = qg4[0]; q[qq][1] = qg4[1]; q[qq][2] = qg4[2]; q[qq][3] = qg4[3];
    }

    float m[NQ], l[NQ];
    float acc[NQ][HD];
    #pragma unroll
    for (int qq = 0; qq < NQ; ++qq) {
        m[qq] = -INFINITY; l[qq] = 0.f;
        #pragma unroll
        for (int d = 0; d < HD; ++d) acc[qq][d] = 0.f;
    }

    for (int kt = 0; kt < S / KT; ++kt) {
        __syncthreads();   // previous tile fully consumed
        {
            const float4* k4 = (const float4*)(K + ((size_t)bh * S + kt * KT) * HD);
            const float4* v4 = (const float4*)(V + ((size_t)bh * S + kt * KT) * HD);
            #pragma unroll
            for (int r = 0; r < 2; ++r) {
                const int idx4 = tid + r * 256;          // 0..511
                const int row = idx4 >> 2, c4 = idx4 & 3;
                ((float4*)(Ks + row * KPAD))[c4] = k4[idx4];
                ((float4*)(Vs + row * KPAD))[c4] = v4[idx4];
            }
            if (tid < KT) {
                float am = 0.f;
                if (!masked && src_mask[b * S + kt * KT + tid] == 0) am = -1000.f;
                Ms[tid] = am;
            }
        }
        __syncthreads();

        // phase 1: scores s[qq][jj]; K row read once per key
        float s[NQ][NK];
        #pragma unroll
        for (int jj = 0; jj < NK; ++jj) {
            const int j = kl + jj * 32;
            const float4* k4 = (const float4*)(Ks + j * KPAD);
            const float4 ka = k4[0], kb = k4[1], kc = k4[2], kd = k4[3];
            const float ms = Ms[j];
            #pragma unroll
            for (int qq = 0; qq < NQ; ++qq) {
                float dot;
                dot = q[qq][0].x * ka.x;
                dot = fmaf(q[qq][0].y, ka.y, dot);
                dot = fmaf(q[qq][0].z, ka.z, dot);
                dot = fmaf(q[qq][0].w, ka.w, dot);
                dot = fmaf(q[qq][1].x, kb.x, dot);
                dot = fmaf(q[qq][1].y, kb.y, dot);
                dot = fmaf(q[qq][1].z, kb.z, dot);
                dot = fmaf(q[qq][1].w, kb.w, dot);
                dot = fmaf(q[qq][2].x, kc.x, dot);
                dot = fmaf(q[qq][2].y, kc.y, dot);
                dot = fmaf(q[qq][2].z, kc.z, dot);
                dot = fmaf(q[qq][2].w, kc.w, dot);
                dot = fmaf(q[qq][3].x, kd.x, dot);
                dot = fmaf(q[qq][3].y, kd.y, dot);
                dot = fmaf(q[qq][3].z, kd.z, dot);
                dot = fmaf(q[qq][3].w, kd.w, dot);
                s[qq][jj] = dot + ms;
            }
        }

        // phase 2: per-query tile max, at-most-one rescale
        #pragma unroll
        for (int qq = 0; qq < NQ; ++qq) {
            float tm = s[qq][0];
            #pragma unroll
            for (int jj = 1; jj < NK; ++jj) tm = fmaxf(tm, s[qq][jj]);
            if (tm > m[qq]) {
                const float alpha = __expf(m[qq] - tm);  // exp(-inf)=0 at kt=0
                l[qq] *= alpha;
                #pragma unroll
                for (int d = 0; d < HD; ++d) acc[qq][d] *= alpha;
                m[qq] = tm;
            }
        }

        // phase 3: V row read once per key, shared across 4 queries
        #pragma unroll
        for (int jj = 0; jj < NK; ++jj) {
            const int j = kl + jj * 32;
            const float4* v4 = (const float4*)(Vs + j * KPAD);
            const float4 va = v4[0], vb = v4[1], vc = v4[2], vd = v4[3];
            #pragma unroll
            for (int qq = 0; qq < NQ; ++qq) {
                const float p = __expf(s[qq][jj] - m[qq]);
                l[qq] += p;
                acc[qq][0]  = fmaf(p, va.x, acc[qq][0]);
                acc[qq][1]  = fmaf(p, va.y, acc[qq][1]);
                acc[qq][2]  = fmaf(p, va.z, acc[qq][2]);
                acc[qq][3]  = fmaf(p, va.w, acc[qq][3]);
                acc[qq][4]  = fmaf(p, vb.x, acc[qq][4]);
                acc[qq][5]  = fmaf(p, vb.y, acc[qq][5]);
                acc[qq][6]  = fmaf(p, vb.z, acc[qq][6]);
                acc[qq][7]  = fmaf(p, vb.w, acc[qq][7]);
                acc[qq][8]  = fmaf(p, vc.x, acc[qq][8]);
                acc[qq][9]  = fmaf(p, vc.y, acc[qq][9]);
                acc[qq][10] = fmaf(p, vc.z, acc[qq][10]);
                acc[qq][11] = fmaf(p, vc.w, acc[qq][11]);
                acc[qq][12] = fmaf(p, vd.x, acc[qq][12]);
                acc[qq][13] = fmaf(p, vd.y, acc[qq][13]);
                acc[qq][14] = fmaf(p, vd.z, acc[qq][14]);
                acc[qq][15] = fmaf(p, vd.w, acc[qq][15]);
            }
        }
    }

    // merge the 32 key-lanes (within wave)
    #pragma unroll
    for (int off = 1; off < 32; off <<= 1) {
        #pragma unroll
        for (int qq = 0; qq < NQ; ++qq) {
            const float m2 = __shfl_xor(m[qq], off);
            const float l2 = __shfl_xor(l[qq], off);
            const float mn = fmaxf(m[qq], m2);
            const float a1 = __expf(m[qq] - mn);
            const float a2 = __expf(m2 - mn);
            l[qq] = l[qq] * a1 + l2 * a2;
            #pragma unroll
            for (int d = 0; d < HD; ++d) {
                const float x2 = __shfl_xor(acc[qq][d], off);
                acc[qq][d] = acc[qq][d] * a1 + x2 * a2;
            }
            m[qq] = mn;
        }
    }

    if (kl == 0) {
        #pragma unroll
        for (int qq = 0; qq < NQ; ++qq) {
            const int s = qrow0 + qq;
            const float inv = 1.f / l[qq];
            // faithful merge: out[b][s][d*8+h], f32
            float* o = out + ((size_t)(b * S + s)) * E + h;
            #pragma unroll
            for (int d = 0; d < HD; ++d)
                o[d * H] = acc[qq][d] * inv;
        }
    }
}

extern "C" void kernel_launch(void* const* d_in, const int* in_sizes, int n_in,
                              void* d_out, int out_size, void* d_ws, size_t ws_size,
                              hipStream_t stream) {
    // size-signature resolution; same-size buffers keep dict relative order
    int ix = 0, im0 = -1, isc = -1, iw[3] = {-1, -1, -1}, nw = 0;
    for (int i = 0; i < n_in; ++i) {
        const int sz = in_sizes[i];
        if (sz == B * S * E) ix = i;
        else if (sz == B * S) { if (im0 < 0) im0 = i; }
        else if (sz == E * E) { if (nw < 3) iw[nw++] = i; }
        else if (sz == 1 && isc < 0) isc = i;
    }
    if (im0 < 0) im0 = 1;
    if (isc < 0) isc = 3;
    if (nw < 3) { iw[0] = n_in - 3; iw[1] = n_in - 2; iw[2] = n_in - 1; }

    const float* x        = (const float*)d_in[ix];
    const int*   src_mask = (const int*)d_in[im0];
    const int*   masked_p = (const int*)d_in[isc];
    const float* wq       = (const float*)d_in[iw[0]];
    const float* wk       = (const float*)d_in[iw[1]];
    const float* wv       = (const float*)d_in[iw[2]];
    float*       out      = (float*)d_out;

    float* Qw = (float*)d_ws;                    // [BH][S][HD] each, 2 MB
    float* Kw = Qw + (size_t)BH * S * HD;
    float* Vw = Kw + (size_t)BH * S * HD;

    qkv_proj<<<B * S / RPB, 128, 0, stream>>>(x, wq, wk, wv, Qw, Kw, Vw);
    attn<<<dim3(S / QT, BH), 256, 0, stream>>>(Qw, Kw, Vw, src_mask, masked_p, out);
}

// Round 24
// 92.159 us; speedup vs baseline: 1.7505x; 1.4192x over previous
//
#include <hip/hip_runtime.h>
#include <hip/hip_bf16.h>

#define B 2
#define S 2048
#define E 128
#define H 8
#define HD 16
#define BH (B*H)

#define RPB 8    // rows per block (qkv_proj)
#define QT 32    // queries per block (attn)
#define NQ 4     // queries per lane
#define NK 4     // keys per lane per tile
#define KT 128   // key tile
#define KPAD 20  // padded row stride (floats) for K/V LDS tiles

// ---- Pass A: order-preserving mask compaction (1 wave per batch). ----
// pos[b*S+s] = compact index if key kept else -1; cnt[b] = #kept.
// Kept = masked!=0 (no mask path) or src_mask==1. Masked keys' softmax
// weight underflows to exactly 0 in f32 (spread << 1000), so dropping
// them is exact. All-masked edge: -1000 shift cancels -> keep all.
__global__ __launch_bounds__(64) void compact_idx(
    const int* __restrict__ mask, const int* __restrict__ masked_p,
    int* __restrict__ pos, int* __restrict__ cnt)
{
    const int b = blockIdx.x, lane = threadIdx.x;
    const int masked = *masked_p;
    int v[32];
    #pragma unroll
    for (int c = 0; c < 32; ++c)
        v[c] = mask[b * S + c * 64 + lane];     // prefetch, 32 in flight

    int base = 0;
    #pragma unroll
    for (int c = 0; c < 32; ++c) {
        const bool keep = (masked != 0) || (v[c] != 0);
        const unsigned long long bal = __ballot(keep);
        const int my = base + (int)__popcll(bal & ((1ULL << lane) - 1ULL));
        pos[b * S + c * 64 + lane] = keep ? my : -1;
        base += (int)__popcll(bal);
    }
    if (base == 0) {                            // all masked: keep all
        #pragma unroll
        for (int c = 0; c < 32; ++c)
            pos[b * S + c * 64 + lane] = c * 64 + lane;
        base = S;
    }
    if (lane == 0) cnt[b] = base;
}

// ---- Pass 0: QKV projection; K/V written COMPACTED via pos. ----
__global__ __launch_bounds__(128) void qkv_proj(
    const float* __restrict__ x,
    const float* __restrict__ wq,
    const float* __restrict__ wk,
    const float* __restrict__ wv,
    const int* __restrict__ pos,
    float* __restrict__ Q, float* __restrict__ Kc, float* __restrict__ Vc)
{
    __shared__ float xs[RPB][E];
    const int row0 = blockIdx.x * RPB;
    const int c    = threadIdx.x;
    #pragma unroll
    for (int rr = 0; rr < RPB; ++rr)
        xs[rr][c] = x[(size_t)(row0 + rr) * E + c];
    __syncthreads();

    float aq[RPB], ak[RPB], av[RPB];
    #pragma unroll
    for (int rr = 0; rr < RPB; ++rr) { aq[rr] = 0.f; ak[rr] = 0.f; av[rr] = 0.f; }

    for (int i = 0; i < E; ++i) {
        const float wqv = wq[i * E + c];
        const float wkv = wk[i * E + c];
        const float wvv = wv[i * E + c];
        #pragma unroll
        for (int rr = 0; rr < RPB; ++rr) {
            const float xv = xs[rr][i];
            aq[rr] = fmaf(xv, wqv, aq[rr]);
            ak[rr] = fmaf(xv, wkv, ak[rr]);
            av[rr] = fmaf(xv, wvv, av[rr]);
        }
    }

    const int h = c & 7, d = c >> 3;            // faithful split: col = d*8+h
    #pragma unroll
    for (int rr = 0; rr < RPB; ++rr) {
        const int row = row0 + rr;
        const int b = row >> 11, s = row & 2047;
        Q[(((size_t)(b * H + h)) * S + s) * HD + d] = aq[rr] * 0.25f;
        const int p_ = pos[row];
        if (p_ >= 0) {
            const size_t offc = (((size_t)(b * H + h)) * S + p_) * HD + d;
            Kc[offc] = ak[rr];
            Vc[offc] = av[rr];
        }
    }
}

// ---- Pass 1: flash attention over COMPACTED keys. ----
// 256 threads = 8 query-quads x 32 key-lanes; NQ=4 queries/lane.
// Tail rows zero-filled with -1e30 bias (all edge cases resolve to p=0).
__global__ __launch_bounds__(256) void attn(
    const float* __restrict__ Q, const float* __restrict__ Kc,
    const float* __restrict__ Vc, const int* __restrict__ cnt,
    float* __restrict__ out)
{
    __shared__ float Ks[KT * KPAD];
    __shared__ float Vs[KT * KPAD];
    __shared__ float Ms[KT];

    const int bh    = blockIdx.y;
    const int b     = bh >> 3;
    const int h     = bh & 7;
    const int qtile = blockIdx.x;
    const int tid   = threadIdx.x;
    const int qg    = tid >> 5;          // 0..7 query quad
    const int kl    = tid & 31;          // key lane
    const int qrow0 = qtile * QT + qg * NQ;
    const int cn    = cnt[b];
    const int nt    = (cn + KT - 1) >> 7;

    float4 q[NQ][4];
    #pragma unroll
    for (int qq = 0; qq < NQ; ++qq) {
        const float4* qg4 = (const float4*)(Q + ((size_t)bh * S + qrow0 + qq) * HD);
        q[qq][0] = qg4[0]; q[qq][1] = qg4[1]; q[qq][2] = qg4[2]; q[qq][3] = qg4[3];
    }

    float m[NQ], l[NQ];
    float acc[NQ][HD];
    #pragma unroll
    for (int qq = 0; qq < NQ; ++qq) {
        m[qq] = -1e30f; l[qq] = 0.f;
        #pragma unroll
        for (int d = 0; d < HD; ++d) acc[qq][d] = 0.f;
    }

    for (int kt = 0; kt < nt; ++kt) {
        __syncthreads();
        const int base = kt * KT;
        {
            const float4* k4 = (const float4*)(Kc + ((size_t)bh * S + base) * HD);
            const float4* v4 = (const float4*)(Vc + ((size_t)bh * S + base) * HD);
            #pragma unroll
            for (int r = 0; r < 2; ++r) {
                const int idx4 = tid + r * 256;          // 0..511
                const int row = idx4 >> 2, c4 = idx4 & 3;
                float4 kv, vv;
                if (base + row < cn) { kv = k4[idx4]; vv = v4[idx4]; }
                else { kv = make_float4(0,0,0,0); vv = make_float4(0,0,0,0); }
                ((float4*)(Ks + row * KPAD))[c4] = kv;
                ((float4*)(Vs + row * KPAD))[c4] = vv;
            }
            if (tid < KT)
                Ms[tid] = (base + tid < cn) ? 0.f : -1e30f;
        }
        __syncthreads();

        // phase 1: scores; K row read once per key, shared by 4 queries
        float s[NQ][NK];
        #pragma unroll
        for (int jj = 0; jj < NK; ++jj) {
            const int j = kl + jj * 32;
            const float4* k4 = (const float4*)(Ks + j * KPAD);
            const float4 ka = k4[0], kb = k4[1], kc = k4[2], kd = k4[3];
            const float ms = Ms[j];
            #pragma unroll
            for (int qq = 0; qq < NQ; ++qq) {
                float dot;
                dot = q[qq][0].x * ka.x;
                dot = fmaf(q[qq][0].y, ka.y, dot);
                dot = fmaf(q[qq][0].z, ka.z, dot);
                dot = fmaf(q[qq][0].w, ka.w, dot);
                dot = fmaf(q[qq][1].x, kb.x, dot);
                dot = fmaf(q[qq][1].y, kb.y, dot);
                dot = fmaf(q[qq][1].z, kb.z, dot);
                dot = fmaf(q[qq][1].w, kb.w, dot);
                dot = fmaf(q[qq][2].x, kc.x, dot);
                dot = fmaf(q[qq][2].y, kc.y, dot);
                dot = fmaf(q[qq][2].z, kc.z, dot);
                dot = fmaf(q[qq][2].w, kc.w, dot);
                dot = fmaf(q[qq][3].x, kd.x, dot);
                dot = fmaf(q[qq][3].y, kd.y, dot);
                dot = fmaf(q[qq][3].z, kd.z, dot);
                dot = fmaf(q[qq][3].w, kd.w, dot);
                s[qq][jj] = dot + ms;
            }
        }

        // phase 2: per-query tile max, at-most-one rescale
        #pragma unroll
        for (int qq = 0; qq < NQ; ++qq) {
            float tm = s[qq][0];
            #pragma unroll
            for (int jj = 1; jj < NK; ++jj) tm = fmaxf(tm, s[qq][jj]);
            if (tm > m[qq]) {
                const float alpha = __expf(m[qq] - tm);
                l[qq] *= alpha;
                #pragma unroll
                for (int d = 0; d < HD; ++d) acc[qq][d] *= alpha;
                m[qq] = tm;
            }
        }

        // phase 3: V row read once per key, shared by 4 queries
        #pragma unroll
        for (int jj = 0; jj < NK; ++jj) {
            const int j = kl + jj * 32;
            const float4* v4 = (const float4*)(Vs + j * KPAD);
            const float4 va = v4[0], vb = v4[1], vc = v4[2], vd = v4[3];
            #pragma unroll
            for (int qq = 0; qq < NQ; ++qq) {
                const float p = __expf(s[qq][jj] - m[qq]);
                l[qq] += p;
                acc[qq][0]  = fmaf(p, va.x, acc[qq][0]);
                acc[qq][1]  = fmaf(p, va.y, acc[qq][1]);
                acc[qq][2]  = fmaf(p, va.z, acc[qq][2]);
                acc[qq][3]  = fmaf(p, va.w, acc[qq][3]);
                acc[qq][4]  = fmaf(p, vb.x, acc[qq][4]);
                acc[qq][5]  = fmaf(p, vb.y, acc[qq][5]);
                acc[qq][6]  = fmaf(p, vb.z, acc[qq][6]);
                acc[qq][7]  = fmaf(p, vb.w, acc[qq][7]);
                acc[qq][8]  = fmaf(p, vc.x, acc[qq][8]);
                acc[qq][9]  = fmaf(p, vc.y, acc[qq][9]);
                acc[qq][10] = fmaf(p, vc.z, acc[qq][10]);
                acc[qq][11] = fmaf(p, vc.w, acc[qq][11]);
                acc[qq][12] = fmaf(p, vd.x, acc[qq][12]);
                acc[qq][13] = fmaf(p, vd.y, acc[qq][13]);
                acc[qq][14] = fmaf(p, vd.z, acc[qq][14]);
                acc[qq][15] = fmaf(p, vd.w, acc[qq][15]);
            }
        }
    }

    // merge the 32 key-lanes (within wave)
    #pragma unroll
    for (int off = 1; off < 32; off <<= 1) {
        #pragma unroll
        for (int qq = 0; qq < NQ; ++qq) {
            const float m2 = __shfl_xor(m[qq], off);
            const float l2 = __shfl_xor(l[qq], off);
            const float mn = fmaxf(m[qq], m2);
            const float a1 = __expf(m[qq] - mn);
            const float a2 = __expf(m2 - mn);
            l[qq] = l[qq] * a1 + l2 * a2;
            #pragma unroll
            for (int d = 0; d < HD; ++d) {
                const float x2 = __shfl_xor(acc[qq][d], off);
                acc[qq][d] = acc[qq][d] * a1 + x2 * a2;
            }
            m[qq] = mn;
        }
    }

    if (kl == 0) {
        #pragma unroll
        for (int qq = 0; qq < NQ; ++qq) {
            const int s = qrow0 + qq;
            const float inv = 1.f / l[qq];
            float* o = out + ((size_t)(b * S + s)) * E + h;   // d8h merge
            #pragma unroll
            for (int d = 0; d < HD; ++d)
                o[d * H] = acc[qq][d] * inv;
        }
    }
}

extern "C" void kernel_launch(void* const* d_in, const int* in_sizes, int n_in,
                              void* d_out, int out_size, void* d_ws, size_t ws_size,
                              hipStream_t stream) {
    int ix = 0, im0 = -1, isc = -1, iw[3] = {-1, -1, -1}, nw = 0;
    for (int i = 0; i < n_in; ++i) {
        const int sz = in_sizes[i];
        if (sz == B * S * E) ix = i;
        else if (sz == B * S) { if (im0 < 0) im0 = i; }
        else if (sz == E * E) { if (nw < 3) iw[nw++] = i; }
        else if (sz == 1 && isc < 0) isc = i;
    }
    if (im0 < 0) im0 = 1;
    if (isc < 0) isc = 3;
    if (nw < 3) { iw[0] = n_in - 3; iw[1] = n_in - 2; iw[2] = n_in - 1; }

    const float* x        = (const float*)d_in[ix];
    const int*   src_mask = (const int*)d_in[im0];
    const int*   masked_p = (const int*)d_in[isc];
    const float* wq       = (const float*)d_in[iw[0]];
    const float* wk       = (const float*)d_in[iw[1]];
    const float* wv       = (const float*)d_in[iw[2]];
    float*       out      = (float*)d_out;

    float* Qw  = (float*)d_ws;                   // [BH][S][HD], 2 MB
    float* Kc  = Qw + (size_t)BH * S * HD;       // compacted K, 2 MB
    float* Vc  = Kc + (size_t)BH * S * HD;       // compacted V, 2 MB
    int*   pos = (int*)(Vc + (size_t)BH * S * HD);  // B*S ints
    int*   cnt = pos + B * S;                    // 2 ints

    compact_idx<<<B, 64, 0, stream>>>(src_mask, masked_p, pos, cnt);
    qkv_proj<<<B * S / RPB, 128, 0, stream>>>(x, wq, wk, wv, pos, Qw, Kc, Vc);
    attn<<<dim3(S / QT, BH), 256, 0, stream>>>(Qw, Kc, Vc, cnt, out);
}

// Round 25
// 63.623 us; speedup vs baseline: 2.5356x; 1.4485x over previous
//
#include <hip/hip_runtime.h>
#include <hip/hip_bf16.h>

#define B 2
#define S 2048
#define E 128
#define H 8
#define HD 16
#define BH (B*H)

#define RPB 8    // rows per block (qkv_proj)
#define KT 128   // key tile (attn)
#define KXS 40   // Kx row stride in ushorts (80 B, conflict-breaking pad)
#define BTS 40   // Bt row stride in ushorts

typedef __attribute__((ext_vector_type(8))) short bf16x8;
typedef __attribute__((ext_vector_type(4))) float f32x4;

__device__ __forceinline__ unsigned short f2b(float f) {   // f32->bf16 RNE
    const unsigned u = __float_as_uint(f);
    return (unsigned short)((u + 0x7FFFu + ((u >> 16) & 1u)) >> 16);
}
__device__ __forceinline__ float b2f(unsigned short u) {
    return __uint_as_float((unsigned)u << 16);
}

// ---- Pass A: order-preserving mask compaction (1 wave per batch). ----
__global__ __launch_bounds__(64) void compact_idx(
    const int* __restrict__ mask, const int* __restrict__ masked_p,
    int* __restrict__ pos, int* __restrict__ cnt)
{
    const int b = blockIdx.x, lane = threadIdx.x;
    const int masked = *masked_p;
    int v[32];
    #pragma unroll
    for (int c = 0; c < 32; ++c)
        v[c] = mask[b * S + c * 64 + lane];

    int base = 0;
    #pragma unroll
    for (int c = 0; c < 32; ++c) {
        const bool keep = (masked != 0) || (v[c] != 0);
        const unsigned long long bal = __ballot(keep);
        const int my = base + (int)__popcll(bal & ((1ULL << lane) - 1ULL));
        pos[b * S + c * 64 + lane] = keep ? my : -1;
        base += (int)__popcll(bal);
    }
    if (base == 0) {                       // all masked: -1000 shift cancels
        #pragma unroll
        for (int c = 0; c < 32; ++c)
            pos[b * S + c * 64 + lane] = c * 64 + lane;
        base = S;
    }
    if (lane == 0) cnt[b] = base;
}

// ---- Pass 0: QKV projection; K/V written COMPACTED via pos. ----
__global__ __launch_bounds__(128) void qkv_proj(
    const float* __restrict__ x,
    const float* __restrict__ wq,
    const float* __restrict__ wk,
    const float* __restrict__ wv,
    const int* __restrict__ pos,
    float* __restrict__ Q, float* __restrict__ Kc, float* __restrict__ Vc)
{
    __shared__ float xs[RPB][E];
    const int row0 = blockIdx.x * RPB;
    const int c    = threadIdx.x;
    #pragma unroll
    for (int rr = 0; rr < RPB; ++rr)
        xs[rr][c] = x[(size_t)(row0 + rr) * E + c];
    __syncthreads();

    float aq[RPB], ak[RPB], av[RPB];
    #pragma unroll
    for (int rr = 0; rr < RPB; ++rr) { aq[rr] = 0.f; ak[rr] = 0.f; av[rr] = 0.f; }

    for (int i = 0; i < E; ++i) {
        const float wqv = wq[i * E + c];
        const float wkv = wk[i * E + c];
        const float wvv = wv[i * E + c];
        #pragma unroll
        for (int rr = 0; rr < RPB; ++rr) {
            const float xv = xs[rr][i];
            aq[rr] = fmaf(xv, wqv, aq[rr]);
            ak[rr] = fmaf(xv, wkv, ak[rr]);
            av[rr] = fmaf(xv, wvv, av[rr]);
        }
    }

    const int h = c & 7, d = c >> 3;       // faithful split: col = d*8+h
    #pragma unroll
    for (int rr = 0; rr < RPB; ++rr) {
        const int row = row0 + rr;
        const int b = row >> 11, s = row & 2047;
        Q[(((size_t)(b * H + h)) * S + s) * HD + d] = aq[rr] * 0.25f;
        const int p_ = pos[row];
        if (p_ >= 0) {
            const size_t offc = (((size_t)(b * H + h)) * S + p_) * HD + d;
            Kc[offc] = ak[rr];
            Vc[offc] = av[rr];
        }
    }
}

// ---- Pass 1: MFMA flash attention over compacted keys. ----
// Block: 128 thr = 2 waves; wave handles 16 queries. Grid (S/32, BH).
// QK: C = K_ext[16k x 32(hi|lo)] x Qfrag -> scores^T (lane: q=l&15, 4 keys).
// PV: A = p (bf16, redistributed), B = [Vhi|Vlo] -> acc (lane: dim=l&15, 4 q).
__global__ __launch_bounds__(128) void attn(
    const float* __restrict__ Q, const float* __restrict__ Kc,
    const float* __restrict__ Vc, const int* __restrict__ cnt,
    float* __restrict__ out)
{
    __shared__ unsigned short Kx[KT * KXS];      // [key][32+pad] hi|lo
    __shared__ unsigned short Bt[8 * 16 * BTS];  // [kb][dim][32+pad] Vhi|Vlo

    const int bh    = blockIdx.y;
    const int b     = bh >> 3;
    const int h     = bh & 7;
    const int qtile = blockIdx.x;        // 0..63
    const int tid   = threadIdx.x;       // 0..127
    const int wid   = tid >> 6;
    const int lane  = tid & 63;
    const int col   = lane & 15;
    const int g     = lane >> 4;         // 0..3
    const int qrow0 = qtile * 32 + wid * 16;
    const int cn    = cnt[b];
    const int nt    = (cn + KT - 1) >> 7;

    // Q B-frags (hi, lo); 0.25 pre-folded. Lane supplies dims 8*(g&1)..+7.
    bf16x8 qh, ql;
    {
        const float* qp = Q + ((size_t)bh * S + qrow0 + col) * HD + 8 * (g & 1);
        #pragma unroll
        for (int i = 0; i < 8; ++i) {
            const float f = qp[i];
            const unsigned short hi = f2b(f);
            qh[i] = (short)hi;
            ql[i] = (short)f2b(f - b2f(hi));
        }
    }

    float m = -1e30f, l = 0.f;
    f32x4 acc = {0.f, 0.f, 0.f, 0.f};

    for (int kt = 0; kt < nt; ++kt) {
        const int base = kt * KT;
        __syncthreads();
        // ---- stage: K_ext (hi|lo) and Bt (V^T hi|lo), one key per thread ----
        {
            const int key = tid;
            const bool real = (base + key) < cn;
            const float4* kr = (const float4*)(Kc + ((size_t)bh * S + base + key) * HD);
            const float4* vr = (const float4*)(Vc + ((size_t)bh * S + base + key) * HD);
            const int kb = key >> 4, k16 = key & 15;
            unsigned short* kx = Kx + key * KXS;
            #pragma unroll
            for (int i4 = 0; i4 < 4; ++i4) {
                float4 kv, vv;
                if (real) { kv = kr[i4]; vv = vr[i4]; }
                else { kv = make_float4(0,0,0,0); vv = make_float4(0,0,0,0); }
                const float kf[4] = {kv.x, kv.y, kv.z, kv.w};
                const float vf[4] = {vv.x, vv.y, vv.z, vv.w};
                #pragma unroll
                for (int j = 0; j < 4; j += 2) {
                    const int d = i4 * 4 + j;
                    // K_ext: pack two hi / two lo as u32 writes
                    const unsigned short h0 = f2b(kf[j]),   h1 = f2b(kf[j+1]);
                    const unsigned short l0 = f2b(kf[j]   - b2f(h0));
                    const unsigned short l1 = f2b(kf[j+1] - b2f(h1));
                    *(unsigned*)(kx + d)      = (unsigned)h0 | ((unsigned)h1 << 16);
                    *(unsigned*)(kx + 16 + d) = (unsigned)l0 | ((unsigned)l1 << 16);
                    // V^T: scattered b16 writes
                    const unsigned short vh0 = f2b(vf[j]),   vh1 = f2b(vf[j+1]);
                    const unsigned short vl0 = f2b(vf[j]   - b2f(vh0));
                    const unsigned short vl1 = f2b(vf[j+1] - b2f(vh1));
                    Bt[(kb * 16 + d) * BTS + k16]          = vh0;
                    Bt[(kb * 16 + d) * BTS + k16 + 16]     = vl0;
                    Bt[(kb * 16 + d + 1) * BTS + k16]      = vh1;
                    Bt[(kb * 16 + d + 1) * BTS + k16 + 16] = vl1;
                }
            }
        }
        __syncthreads();

        // ---- phase A: scores^T via 2 MFMAs per 16-key block ----
        f32x4 sc[8];
        #pragma unroll
        for (int kb = 0; kb < 8; ++kb) {
            const bf16x8 ka = *(const bf16x8*)(Kx + (kb * 16 + col) * KXS + 8 * g);
            f32x4 c = {0.f, 0.f, 0.f, 0.f};
            c = __builtin_amdgcn_mfma_f32_16x16x32_bf16(ka, qh, c, 0, 0, 0);
            c = __builtin_amdgcn_mfma_f32_16x16x32_bf16(ka, ql, c, 0, 0, 0);
            sc[kb] = c;
        }
        if (base + KT > cn) {                 // tail: mask fake keys
            #pragma unroll
            for (int kb = 0; kb < 8; ++kb)
                #pragma unroll
                for (int r = 0; r < 4; ++r)
                    if (base + kb * 16 + 4 * g + r >= cn) sc[kb][r] = -1e30f;
        }

        // ---- phase B: tile max (per query col) + branchless rescale ----
        float tm = sc[0][0];
        #pragma unroll
        for (int kb = 0; kb < 8; ++kb)
            #pragma unroll
            for (int r = 0; r < 4; ++r) tm = fmaxf(tm, sc[kb][r]);
        tm = fmaxf(tm, __shfl_xor(tm, 16));
        tm = fmaxf(tm, __shfl_xor(tm, 32));
        const float mn = fmaxf(m, tm);
        const float alpha = __expf(m - mn);   // m=-1e30 first tile -> 0
        m = mn;
        l *= alpha;
        #pragma unroll
        for (int r = 0; r < 4; ++r)
            acc[r] *= __shfl(alpha, 4 * g + r);   // alpha of query 4g+r

        // ---- phase C: exp, pack, redistribute, PV MFMA ----
        #pragma unroll
        for (int kb = 0; kb < 8; ++kb) {
            const float p0 = __expf(sc[kb][0] - m);
            const float p1 = __expf(sc[kb][1] - m);
            const float p2 = __expf(sc[kb][2] - m);
            const float p3 = __expf(sc[kb][3] - m);
            float bl = p0 + p1 + p2 + p3;
            bl += __shfl_xor(bl, 16);
            bl += __shfl_xor(bl, 32);
            l += bl;

            const unsigned u01 = (unsigned)f2b(p0) | ((unsigned)f2b(p1) << 16);
            const unsigned u23 = (unsigned)f2b(p2) | ((unsigned)f2b(p3) << 16);
            const int s0 = col + 16 * (2 * (g & 1));
            const int s1 = s0 + 16;
            union { unsigned u[4]; bf16x8 v; } pa;
            pa.u[0] = (unsigned)__shfl((int)u01, s0);
            pa.u[1] = (unsigned)__shfl((int)u23, s0);
            pa.u[2] = (unsigned)__shfl((int)u01, s1);
            pa.u[3] = (unsigned)__shfl((int)u23, s1);

            const bf16x8 vb = *(const bf16x8*)(Bt + (kb * 16 + col) * BTS + 8 * g);
            acc = __builtin_amdgcn_mfma_f32_16x16x32_bf16(pa.v, vb, acc, 0, 0, 0);
        }
    }

    // ---- epilogue: normalize, d8h merge: out[b][q][dim*8+h] ----
    const float inv = 1.f / l;                // per query col
    #pragma unroll
    for (int r = 0; r < 4; ++r) {
        const float ir = __shfl(inv, 4 * g + r);
        out[((size_t)(b * S + qrow0 + 4 * g + r)) * E + col * 8 + h] = acc[r] * ir;
    }
}

extern "C" void kernel_launch(void* const* d_in, const int* in_sizes, int n_in,
                              void* d_out, int out_size, void* d_ws, size_t ws_size,
                              hipStream_t stream) {
    int ix = 0, im0 = -1, isc = -1, iw[3] = {-1, -1, -1}, nw = 0;
    for (int i = 0; i < n_in; ++i) {
        const int sz = in_sizes[i];
        if (sz == B * S * E) ix = i;
        else if (sz == B * S) { if (im0 < 0) im0 = i; }
        else if (sz == E * E) { if (nw < 3) iw[nw++] = i; }
        else if (sz == 1 && isc < 0) isc = i;
    }
    if (im0 < 0) im0 = 1;
    if (isc < 0) isc = 3;
    if (nw < 3) { iw[0] = n_in - 3; iw[1] = n_in - 2; iw[2] = n_in - 1; }

    const float* x        = (const float*)d_in[ix];
    const int*   src_mask = (const int*)d_in[im0];
    const int*   masked_p = (const int*)d_in[isc];
    const float* wq       = (const float*)d_in[iw[0]];
    const float* wk       = (const float*)d_in[iw[1]];
    const float* wv       = (const float*)d_in[iw[2]];
    float*       out      = (float*)d_out;

    float* Qw  = (float*)d_ws;                   // [BH][S][HD]
    float* Kc  = Qw + (size_t)BH * S * HD;
    float* Vc  = Kc + (size_t)BH * S * HD;
    int*   pos = (int*)(Vc + (size_t)BH * S * HD);
    int*   cnt = pos + B * S;

    compact_idx<<<B, 64, 0, stream>>>(src_mask, masked_p, pos, cnt);
    qkv_proj<<<B * S / RPB, 128, 0, stream>>>(x, wq, wk, wv, pos, Qw, Kc, Vc);
    attn<<<dim3(S / 32, BH), 128, 0, stream>>>(Qw, Kc, Vc, cnt, out);
}

// Round 26
// 54.262 us; speedup vs baseline: 2.9730x; 1.1725x over previous
//
#include <hip/hip_runtime.h>
#include <hip/hip_bf16.h>

#define B 2
#define S 2048
#define E 128
#define H 8
#define HD 16
#define BH (B*H)

#define RPB 8    // rows per block (qkv_proj)
#define KT 128   // key tile (attn)

typedef __attribute__((ext_vector_type(8))) short bf16x8;
typedef __attribute__((ext_vector_type(4))) float f32x4;

__device__ __forceinline__ unsigned short f2b(float f) {   // f32->bf16 RNE
    const unsigned u = __float_as_uint(f);
    return (unsigned short)((u + 0x7FFFu + ((u >> 16) & 1u)) >> 16);
}
__device__ __forceinline__ float b2f(unsigned short u) {
    return __uint_as_float((unsigned)u << 16);
}

// ---- Pass A: order-preserving mask compaction (1 wave per batch). ----
__global__ __launch_bounds__(64) void compact_idx(
    const int* __restrict__ mask, const int* __restrict__ masked_p,
    int* __restrict__ pos, int* __restrict__ cnt)
{
    const int b = blockIdx.x, lane = threadIdx.x;
    const int masked = *masked_p;
    int v[32];
    #pragma unroll
    for (int c = 0; c < 32; ++c)
        v[c] = mask[b * S + c * 64 + lane];

    int base = 0;
    #pragma unroll
    for (int c = 0; c < 32; ++c) {
        const bool keep = (masked != 0) || (v[c] != 0);
        const unsigned long long bal = __ballot(keep);
        const int my = base + (int)__popcll(bal & ((1ULL << lane) - 1ULL));
        pos[b * S + c * 64 + lane] = keep ? my : -1;
        base += (int)__popcll(bal);
    }
    if (base == 0) {                       // all masked: -1000 shift cancels
        #pragma unroll
        for (int c = 0; c < 32; ++c)
            pos[b * S + c * 64 + lane] = c * 64 + lane;
        base = S;
    }
    if (lane == 0) cnt[b] = base;
}

// ---- Pass B: zero the ragged tail rows of Kx/Bt (avoid Inf/NaN garbage). --
__global__ __launch_bounds__(64) void zero_tail(
    const int* __restrict__ cnt,
    unsigned short* __restrict__ Kxg, unsigned short* __restrict__ Btg)
{
    const int bh = blockIdx.x, b = bh >> 3;
    const int cn = cnt[b];
    const int pad = ((cn + KT - 1) / KT) * KT;
    const int nrows = pad - cn;
    unsigned short* KxB = Kxg + (size_t)bh * S * 32;
    unsigned short* BtB = Btg + (size_t)bh * S * 32;
    for (int idx = threadIdx.x; idx < nrows * 16; idx += 64) {
        const int row = cn + (idx >> 4), d = idx & 15;
        KxB[row * 32 + d]      = 0;
        KxB[row * 32 + 16 + d] = 0;
        BtB[((row >> 4) * 16 + d) * 32 + (row & 15)]      = 0;
        BtB[((row >> 4) * 16 + d) * 32 + (row & 15) + 16] = 0;
    }
}

// ---- Pass 0: QKV projection; K/V written compacted, MFMA-ready bf16. ----
// Kx[bh][key][32]: hi dims 0-15 | lo dims 0-15.
// Bt[bh][key>>4][dim][32]: Vhi keys 0-15 | Vlo keys 0-15.
__global__ __launch_bounds__(128) void qkv_proj(
    const float* __restrict__ x,
    const float* __restrict__ wq,
    const float* __restrict__ wk,
    const float* __restrict__ wv,
    const int* __restrict__ pos,
    float* __restrict__ Q,
    unsigned short* __restrict__ Kxg, unsigned short* __restrict__ Btg)
{
    __shared__ float xs[RPB][E];
    const int row0 = blockIdx.x * RPB;
    const int c    = threadIdx.x;
    #pragma unroll
    for (int rr = 0; rr < RPB; ++rr)
        xs[rr][c] = x[(size_t)(row0 + rr) * E + c];
    __syncthreads();

    float aq[RPB], ak[RPB], av[RPB];
    #pragma unroll
    for (int rr = 0; rr < RPB; ++rr) { aq[rr] = 0.f; ak[rr] = 0.f; av[rr] = 0.f; }

    for (int i = 0; i < E; ++i) {
        const float wqv = wq[i * E + c];
        const float wkv = wk[i * E + c];
        const float wvv = wv[i * E + c];
        #pragma unroll
        for (int rr = 0; rr < RPB; ++rr) {
            const float xv = xs[rr][i];
            aq[rr] = fmaf(xv, wqv, aq[rr]);
            ak[rr] = fmaf(xv, wkv, ak[rr]);
            av[rr] = fmaf(xv, wvv, av[rr]);
        }
    }

    const int h = c & 7, d = c >> 3;       // faithful split: col = d*8+h
    unsigned short* KxB = Kxg + (size_t)(0) ;  // per-row below
    #pragma unroll
    for (int rr = 0; rr < RPB; ++rr) {
        const int row = row0 + rr;
        const int b = row >> 11, s = row & 2047;
        const int bh = b * H + h;
        Q[(((size_t)bh) * S + s) * HD + d] = aq[rr] * 0.25f;
        const int p_ = pos[row];
        if (p_ >= 0) {
            const unsigned short kh = f2b(ak[rr]);
            const unsigned short kl = f2b(ak[rr] - b2f(kh));
            const unsigned short vh = f2b(av[rr]);
            const unsigned short vl = f2b(av[rr] - b2f(vh));
            unsigned short* kx = Kxg + (size_t)bh * S * 32 + (size_t)p_ * 32;
            kx[d]      = kh;
            kx[16 + d] = kl;
            unsigned short* bt = Btg + (size_t)bh * S * 32
                               + ((size_t)(p_ >> 4) * 16 + d) * 32 + (p_ & 15);
            bt[0]  = vh;
            bt[16] = vl;
        }
    }
    (void)KxB;
}

// ---- Pass 1: MFMA flash attention, fragments direct from global (L2). ----
// Block 128 = 2 waves; wave handles 16 queries. No LDS, no barriers.
__global__ __launch_bounds__(128) void attn(
    const float* __restrict__ Q,
    const unsigned short* __restrict__ Kxg,
    const unsigned short* __restrict__ Btg,
    const int* __restrict__ cnt,
    float* __restrict__ out)
{
    const int bh    = blockIdx.y;
    const int b     = bh >> 3;
    const int h     = bh & 7;
    const int qtile = blockIdx.x;        // 0..63
    const int tid   = threadIdx.x;       // 0..127
    const int wid   = tid >> 6;
    const int lane  = tid & 63;
    const int col   = lane & 15;
    const int g     = lane >> 4;         // 0..3
    const int qrow0 = qtile * 32 + wid * 16;
    const int cn    = cnt[b];
    const int nt    = (cn + KT - 1) >> 7;

    const unsigned short* KxB = Kxg + (size_t)bh * S * 32;
    const unsigned short* BtB = Btg + (size_t)bh * S * 32;

    // Q B-frags (hi, lo); 0.25 pre-folded. Lane supplies dims 8*(g&1)..+7.
    bf16x8 qh, ql;
    {
        const float* qp = Q + ((size_t)bh * S + qrow0 + col) * HD + 8 * (g & 1);
        #pragma unroll
        for (int i = 0; i < 8; ++i) {
            const float f = qp[i];
            const unsigned short hi = f2b(f);
            qh[i] = (short)hi;
            ql[i] = (short)f2b(f - b2f(hi));
        }
    }

    float m = -1e30f, l = 0.f;
    f32x4 acc = {0.f, 0.f, 0.f, 0.f};

    for (int kt = 0; kt < nt; ++kt) {
        const int base = kt * KT;

        // ---- phase A: scores^T via 2 MFMAs per 16-key block ----
        f32x4 sc[8];
        #pragma unroll
        for (int kb = 0; kb < 8; ++kb) {
            const bf16x8 ka = *(const bf16x8*)(
                KxB + (size_t)(base + kb * 16 + col) * 32 + 8 * g);
            f32x4 c = {0.f, 0.f, 0.f, 0.f};
            c = __builtin_amdgcn_mfma_f32_16x16x32_bf16(ka, qh, c, 0, 0, 0);
            c = __builtin_amdgcn_mfma_f32_16x16x32_bf16(ka, ql, c, 0, 0, 0);
            sc[kb] = c;
        }
        if (base + KT > cn) {                 // tail: mask fake keys
            #pragma unroll
            for (int kb = 0; kb < 8; ++kb)
                #pragma unroll
                for (int r = 0; r < 4; ++r)
                    if (base + kb * 16 + 4 * g + r >= cn) sc[kb][r] = -1e30f;
        }

        // ---- phase B: tile max (per query col) + branchless rescale ----
        float tm = sc[0][0];
        #pragma unroll
        for (int kb = 0; kb < 8; ++kb)
            #pragma unroll
            for (int r = 0; r < 4; ++r) tm = fmaxf(tm, sc[kb][r]);
        tm = fmaxf(tm, __shfl_xor(tm, 16));
        tm = fmaxf(tm, __shfl_xor(tm, 32));
        const float mn = fmaxf(m, tm);
        const float alpha = __expf(m - mn);   // m=-1e30 first tile -> 0
        m = mn;
        l *= alpha;
        #pragma unroll
        for (int r = 0; r < 4; ++r)
            acc[r] *= __shfl(alpha, 4 * g + r);

        // ---- phase C: exp, pack, redistribute, PV MFMA ----
        #pragma unroll
        for (int kb = 0; kb < 8; ++kb) {
            const float p0 = __expf(sc[kb][0] - m);
            const float p1 = __expf(sc[kb][1] - m);
            const float p2 = __expf(sc[kb][2] - m);
            const float p3 = __expf(sc[kb][3] - m);
            float bl = p0 + p1 + p2 + p3;
            bl += __shfl_xor(bl, 16);
            bl += __shfl_xor(bl, 32);
            l += bl;

            const unsigned u01 = (unsigned)f2b(p0) | ((unsigned)f2b(p1) << 16);
            const unsigned u23 = (unsigned)f2b(p2) | ((unsigned)f2b(p3) << 16);
            const int s0 = col + 16 * (2 * (g & 1));
            const int s1 = s0 + 16;
            union { unsigned u[4]; bf16x8 v; } pa;
            pa.u[0] = (unsigned)__shfl((int)u01, s0);
            pa.u[1] = (unsigned)__shfl((int)u23, s0);
            pa.u[2] = (unsigned)__shfl((int)u01, s1);
            pa.u[3] = (unsigned)__shfl((int)u23, s1);

            const bf16x8 vb = *(const bf16x8*)(
                BtB + (size_t)((base >> 4) + kb) * 512 + col * 32 + 8 * g);
            acc = __builtin_amdgcn_mfma_f32_16x16x32_bf16(pa.v, vb, acc, 0, 0, 0);
        }
    }

    // ---- epilogue: normalize, d8h merge: out[b][q][dim*8+h] ----
    const float inv = 1.f / l;
    #pragma unroll
    for (int r = 0; r < 4; ++r) {
        const float ir = __shfl(inv, 4 * g + r);
        out[((size_t)(b * S + qrow0 + 4 * g + r)) * E + col * 8 + h] = acc[r] * ir;
    }
}

extern "C" void kernel_launch(void* const* d_in, const int* in_sizes, int n_in,
                              void* d_out, int out_size, void* d_ws, size_t ws_size,
                              hipStream_t stream) {
    int ix = 0, im0 = -1, isc = -1, iw[3] = {-1, -1, -1}, nw = 0;
    for (int i = 0; i < n_in; ++i) {
        const int sz = in_sizes[i];
        if (sz == B * S * E) ix = i;
        else if (sz == B * S) { if (im0 < 0) im0 = i; }
        else if (sz == E * E) { if (nw < 3) iw[nw++] = i; }
        else if (sz == 1 && isc < 0) isc = i;
    }
    if (im0 < 0) im0 = 1;
    if (isc < 0) isc = 3;
    if (nw < 3) { iw[0] = n_in - 3; iw[1] = n_in - 2; iw[2] = n_in - 1; }

    const float* x        = (const float*)d_in[ix];
    const int*   src_mask = (const int*)d_in[im0];
    const int*   masked_p = (const int*)d_in[isc];
    const float* wq       = (const float*)d_in[iw[0]];
    const float* wk       = (const float*)d_in[iw[1]];
    const float* wv       = (const float*)d_in[iw[2]];
    float*       out      = (float*)d_out;

    float*          Qw  = (float*)d_ws;                          // 2 MB
    unsigned short* Kxg = (unsigned short*)(Qw + (size_t)BH * S * HD);  // 2 MB
    unsigned short* Btg = Kxg + (size_t)BH * S * 32;             // 2 MB
    int*            pos = (int*)(Btg + (size_t)BH * S * 32);
    int*            cnt = pos + B * S;

    compact_idx<<<B, 64, 0, stream>>>(src_mask, masked_p, pos, cnt);
    zero_tail<<<BH, 64, 0, stream>>>(cnt, Kxg, Btg);
    qkv_proj<<<B * S / RPB, 128, 0, stream>>>(x, wq, wk, wv, pos, Qw, Kxg, Btg);
    attn<<<dim3(S / 32, BH), 128, 0, stream>>>(Qw, Kxg, Btg, cnt, out);
}